// Round 6
// baseline (1419.564 us; speedup 1.0000x reference)
//
#include <hip/hip_runtime.h>

// 5-layer GRU, H=20, B=256, T=4096, fp32. PyTorch GRU math.
// One block per batch element; 5 waves = one per layer, pipelined over
// KK-timestep chunks. Lane g owns gate g (20-FMA hh matvec); producer wave
// computes the next layer's input projection from its h-broadcast SGPRs.
//
// R5 (stall-bound per R4: VALUBusy 61%, extra issue absorbed free):
//  - KK 16->32: halves the 260 block-wide barriers and their wave-skew cost
//  - lag-by-one proj: proj(h_{t-1}) issued in the ~120-cyc ds_bpermute
//    shadow of timestep t (data-independent; fills previously idle issue)
//  - pre-scaled weights: -log2e folded into r/z rows, -2log2e into n rows
//    -> sigmoid/tanh lose their leading dependent v_mul (chain shortening)

#define HH 20
#define GG 60
#define NL 5
#define BB 256
#define TT 4096
#define KK 32
#define NC (TT / KK)

struct Params {
  const float* x;
  const float* wih[NL];
  const float* whh[NL];
  const float* bih[NL];
  const float* bhh[NL];
  const float* wout;
  const float* bout;
  float* out;
};

__device__ __forceinline__ float bcast(float v, int j) {        // j: imm
  return __int_as_float(__builtin_amdgcn_readlane(__float_as_int(v), j));
}
__device__ __forceinline__ float bcast_dyn(float v, int j) {    // j: sgpr
  return __int_as_float(__builtin_amdgcn_readlane(__float_as_int(v), j));
}
__device__ __forceinline__ float shfl_idx(float v, int byteidx) {
  return __int_as_float(__builtin_amdgcn_ds_bpermute(byteidx, __float_as_int(v)));
}
// inputs pre-scaled by -log2e: sigmoid(x) = rcp(1 + exp2(x_scaled))
__device__ __forceinline__ float fsig_s(float xs) {
  return __builtin_amdgcn_rcpf(1.0f + __builtin_amdgcn_exp2f(xs));
}
// inputs pre-scaled by -2log2e: tanh(y) = 2*rcp(1 + exp2(y_scaled)) - 1
__device__ __forceinline__ float ftanh_s(float ys) {
  return fmaf(2.0f, __builtin_amdgcn_rcpf(1.0f + __builtin_amdgcn_exp2f(ys)), -1.0f);
}

__global__ __launch_bounds__(NL * 64, 1) void gru5_kernel(Params p) {
  // xg handoff (pre-scaled preacts). Rows 0..KK+1; producer writes proj of
  // h_{t-1} at row t (lagged into the bpermute shadow) + peel at row KK;
  // consumer reads row t+1 for its time t; prefetch touches row KK+1 (junk).
  __shared__ float xbuf[2][NL - 1][KK + 2][64];
  __shared__ float yp[NL];

  const int tid = threadIdx.x;
  const int l = tid >> 6;          // wave index == layer
  const int lane = tid & 63;
  const int b = blockIdx.x;
  const int g = lane < GG ? lane : GG - 1;            // gate owned by lane
  const int gn = lane < HH ? lane + 2 * HH : GG - 1;  // n-gate column for unit lane

  const float S1 = -1.44269504088896f;   // -log2(e)      (r/z rows)
  const float S2 = -2.88539008177793f;   // -2*log2(e)    (n rows)
  const float scg = (g < 2 * HH) ? S1 : S2;

  // ---- weights into registers, pre-scaled ----
  float whh_r[HH];
  {
    const float* W = p.whh[l];
    #pragma unroll
    for (int j = 0; j < HH; ++j) whh_r[j] = W[g * HH + j] * scg;
  }
  // hh accumulator init: b_hh only for n-gate rows (r/z b_hh folded into xg)
  const float binit = (g >= 2 * HH) ? p.bhh[l][g] * S2 : 0.0f;

  // producer weights: next layer's ih row for gate g (+ folded biases)
  float wnx[HH];
  float bnx = 0.0f;
  if (l < NL - 1) {
    const float* W = p.wih[l + 1];
    #pragma unroll
    for (int j = 0; j < HH; ++j) wnx[j] = W[g * HH + j] * scg;
    bnx = (p.bih[l + 1][g] + (g < 2 * HH ? p.bhh[l + 1][g] : 0.0f)) * scg;
  }
  // layer 0: scalar input weights (own gate + the n-gate of unit `lane`)
  float w0own = 0.f, b0own = 0.f, w0n = 0.f, b0n = 0.f;
  if (l == 0) {
    w0own = p.wih[0][g] * scg;
    b0own = (p.bih[0][g] + (g < 2 * HH ? p.bhh[0][g] : 0.0f)) * scg;
    w0n = p.wih[0][gn] * S2;
    b0n = p.bih[0][gn] * S2;          // b_ih only (b_hh_n stays in binit)
  }

  const int idx20 = ((lane + 20) & 63) << 2;   // bpermute byte indices
  const int idx40 = ((lane + 40) & 63) << 2;

  float hreg = 0.0f;               // lanes 0..19 carry h[unit] (true scale)
  float hs[HH];                    // wave-uniform broadcast of h (SGPRs)
  #pragma unroll
  for (int j = 0; j < HH; ++j) hs[j] = 0.0f;

  const float* xrow = p.x + (size_t)b * TT;
  float* hout = p.out + (size_t)b * TT * HH;

  // prime layer-0 x stage for chunk 0 (lanes 0..KK-1 hold the chunk's x)
  float xstage = 0.0f;
  if (l == 0 && lane < KK) xstage = xrow[lane];

  for (int s = 0; s < NC + NL - 1; ++s) {
    const int c = s - l;           // this wave's chunk (wave-uniform)
    if (c >= 0 && c < NC) {
      const int pr = (s + 1) & 1;  // read buffer
      const int pc = s & 1;        // write buffer

      if (l == 0) {
        float* dst = &xbuf[pc][0][0][0];
        // prefetch next chunk's x (a whole chunk of latency to hide)
        float xnl = 0.0f;
        if (lane < KK && c + 1 < NC) xnl = xrow[(c + 1) * KK + lane];
        float xv = bcast_dyn(xstage, 0);
        float xr_c = fmaf(w0own, xv, b0own);
        float xn_c = fmaf(w0n, xv, b0n);
        for (int t = 0; t < KK; ++t) {
          // chain head: matvec on hs = h_{t-1}
          float a0 = binit, a1 = 0.f, a2 = 0.f, a3 = 0.f;
          #pragma unroll
          for (int j = 0; j < HH; j += 4) {
            a0 = fmaf(whh_r[j],     hs[j],     a0);
            a1 = fmaf(whh_r[j + 1], hs[j + 1], a1);
            a2 = fmaf(whh_r[j + 2], hs[j + 2], a2);
            a3 = fmaf(whh_r[j + 3], hs[j + 3], a3);
          }
          const float gh = (a0 + a1) + (a2 + a3);
          const float sv = xr_c + gh;
          const float szn = shfl_idx(sv, idx20);    // issue bpermutes...
          const float ghn = shfl_idx(gh, idx40);
          // ...shadow: proj(h_{t-1}) -> row t, and next-x staging
          {
            float c0 = bnx, c1 = 0.f;
            #pragma unroll
            for (int j = 0; j < HH; j += 2) {
              c0 = fmaf(wnx[j],     hs[j],     c0);
              c1 = fmaf(wnx[j + 1], hs[j + 1], c1);
            }
            dst[t * 64 + lane] = c0 + c1;
          }
          float xvn = bcast_dyn(xstage, (t + 1) & (KK - 1));  // wrap: dead
          float xr_n = fmaf(w0own, xvn, b0own);
          float xn_n = fmaf(w0n, xvn, b0n);
          // consume bpermutes -> nonlinearity -> update
          const float r = fsig_s(sv);
          const float z = fsig_s(szn);
          const float n = ftanh_s(fmaf(r, ghn, xn_c));
          hreg = fmaf(z, hreg - n, n);
          #pragma unroll
          for (int j = 0; j < HH; ++j) hs[j] = bcast(hreg, j);
          xr_c = xr_n; xn_c = xn_n;
        }
        // peel: proj(h_{KK-1}) -> row KK
        {
          float c0 = bnx, c1 = 0.f;
          #pragma unroll
          for (int j = 0; j < HH; j += 2) {
            c0 = fmaf(wnx[j],     hs[j],     c0);
            c1 = fmaf(wnx[j + 1], hs[j + 1], c1);
          }
          dst[KK * 64 + lane] = c0 + c1;
        }
        xstage = xnl;
      } else if (l < NL - 1) {
        const float* src = &xbuf[pr][l - 1][0][0];
        float* dst = &xbuf[pc][l][0][0];
        float xr_c = src[64 + g];
        float xn_c = src[64 + gn];
        for (int t = 0; t < KK; ++t) {
          float a0 = binit, a1 = 0.f, a2 = 0.f, a3 = 0.f;
          #pragma unroll
          for (int j = 0; j < HH; j += 4) {
            a0 = fmaf(whh_r[j],     hs[j],     a0);
            a1 = fmaf(whh_r[j + 1], hs[j + 1], a1);
            a2 = fmaf(whh_r[j + 2], hs[j + 2], a2);
            a3 = fmaf(whh_r[j + 3], hs[j + 3], a3);
          }
          const float gh = (a0 + a1) + (a2 + a3);
          const float sv = xr_c + gh;
          const float szn = shfl_idx(sv, idx20);
          const float ghn = shfl_idx(gh, idx40);
          // shadow: proj(h_{t-1}) -> row t; prefetch x for t+1 (row t+2)
          {
            float c0 = bnx, c1 = 0.f;
            #pragma unroll
            for (int j = 0; j < HH; j += 2) {
              c0 = fmaf(wnx[j],     hs[j],     c0);
              c1 = fmaf(wnx[j + 1], hs[j + 1], c1);
            }
            dst[t * 64 + lane] = c0 + c1;
          }
          const float xr_n = src[(t + 2) * 64 + g];
          const float xn_n = src[(t + 2) * 64 + gn];
          const float r = fsig_s(sv);
          const float z = fsig_s(szn);
          const float n = ftanh_s(fmaf(r, ghn, xn_c));
          hreg = fmaf(z, hreg - n, n);
          #pragma unroll
          for (int j = 0; j < HH; ++j) hs[j] = bcast(hreg, j);
          xr_c = xr_n; xn_c = xn_n;
        }
        {
          float c0 = bnx, c1 = 0.f;
          #pragma unroll
          for (int j = 0; j < HH; j += 2) {
            c0 = fmaf(wnx[j],     hs[j],     c0);
            c1 = fmaf(wnx[j + 1], hs[j + 1], c1);
          }
          dst[KK * 64 + lane] = c0 + c1;
        }
      } else {
        const float* src = &xbuf[pr][l - 1][0][0];
        float* hp = hout + (size_t)c * KK * HH;
        float xr_c = src[64 + g];
        float xn_c = src[64 + gn];
        for (int t = 0; t < KK; ++t) {
          float a0 = binit, a1 = 0.f, a2 = 0.f, a3 = 0.f;
          #pragma unroll
          for (int j = 0; j < HH; j += 4) {
            a0 = fmaf(whh_r[j],     hs[j],     a0);
            a1 = fmaf(whh_r[j + 1], hs[j + 1], a1);
            a2 = fmaf(whh_r[j + 2], hs[j + 2], a2);
            a3 = fmaf(whh_r[j + 3], hs[j + 3], a3);
          }
          const float gh = (a0 + a1) + (a2 + a3);
          const float sv = xr_c + gh;
          const float szn = shfl_idx(sv, idx20);
          const float ghn = shfl_idx(gh, idx40);
          const float xr_n = src[(t + 2) * 64 + g];
          const float xn_n = src[(t + 2) * 64 + gn];
          const float r = fsig_s(sv);
          const float z = fsig_s(szn);
          const float n = ftanh_s(fmaf(r, ghn, xn_c));
          hreg = fmaf(z, hreg - n, n);
          if (lane < HH) hp[t * HH + lane] = hreg;   // fire-and-forget
          #pragma unroll
          for (int j = 0; j < HH; ++j) hs[j] = bcast(hreg, j);
          xr_c = xr_n; xn_c = xn_n;
        }
      }

      // ---- epilogue at last chunk: h_n + y_hat partial ----
      if (c == NC - 1) {
        if (lane < HH)
          p.out[(size_t)BB * TT * HH + (size_t)b * NL * HH + l * HH + lane] = hreg;
        float pp = (lane < HH) ? hreg * p.wout[l * HH + lane] : 0.0f;
        #pragma unroll
        for (int off = 32; off > 0; off >>= 1) pp += __shfl_down(pp, off);
        if (lane == 0) yp[l] = pp;
      }
    }
    __syncthreads();
  }

  if (tid == 0) {
    float y = p.bout[0];
    #pragma unroll
    for (int ll = 0; ll < NL; ++ll) y += yp[ll];
    p.out[(size_t)BB * TT * HH + (size_t)BB * NL * HH + b] = y;
  }
}

extern "C" void kernel_launch(void* const* d_in, const int* in_sizes, int n_in,
                              void* d_out, int out_size, void* d_ws, size_t ws_size,
                              hipStream_t stream) {
  Params p;
  p.x = (const float*)d_in[0];
  for (int l = 0; l < NL; ++l) {
    p.wih[l] = (const float*)d_in[1 + 4 * l];
    p.whh[l] = (const float*)d_in[2 + 4 * l];
    p.bih[l] = (const float*)d_in[3 + 4 * l];
    p.bhh[l] = (const float*)d_in[4 + 4 * l];
  }
  p.wout = (const float*)d_in[1 + 4 * NL];
  p.bout = (const float*)d_in[2 + 4 * NL];
  p.out = (float*)d_out;

  gru5_kernel<<<BB, NL * 64, 0, stream>>>(p);
}

// Round 7
// 1240.518 us; speedup vs baseline: 1.1443x; 1.1443x over previous
//
#include <hip/hip_runtime.h>

// 5-layer GRU, H=20, B=256, T=4096, fp32. PyTorch GRU math.
// One block per batch element; 5 waves = one per layer. Lane g owns gate g
// (20-FMA hh matvec); producer wave computes the next layer's input
// projection from its h-broadcast SGPRs. Pre-scaled weights (-log2e on r/z
// rows, -2log2e on n rows) so sigmoid/tanh need no leading multiply.
//
// R6: NO per-chunk __syncthreads. R5 disproved the barrier-count theory
// (fewer barriers = slower); the cost is the max-of-5-waves lockstep. Now:
// pairwise flag sync on a depth-4 ring (prog[l]/cons[l] in LDS, volatile
// polls + s_sleep). Layers drift up to 4 chunks, absorbing transient stalls
// (layer-0 global x loads, layer-4 stores, DS queuing). One final
// __syncthreads before the y reduction only.

#define HH 20
#define GG 60
#define NL 5
#define BB 256
#define TT 4096
#define KK 16
#define NC (TT / KK)
#define RD 4            // ring depth (chunks of drift allowed)

struct Params {
  const float* x;
  const float* wih[NL];
  const float* whh[NL];
  const float* bih[NL];
  const float* bhh[NL];
  const float* wout;
  const float* bout;
  float* out;
};

__device__ __forceinline__ float bcast(float v, int j) {        // j: imm
  return __int_as_float(__builtin_amdgcn_readlane(__float_as_int(v), j));
}
__device__ __forceinline__ float bcast_dyn(float v, int j) {    // j: sgpr
  return __int_as_float(__builtin_amdgcn_readlane(__float_as_int(v), j));
}
__device__ __forceinline__ float shfl_idx(float v, int byteidx) {
  return __int_as_float(__builtin_amdgcn_ds_bpermute(byteidx, __float_as_int(v)));
}
// inputs pre-scaled by -log2e: sigmoid(x) = rcp(1 + exp2(x_scaled))
__device__ __forceinline__ float fsig_s(float xs) {
  return __builtin_amdgcn_rcpf(1.0f + __builtin_amdgcn_exp2f(xs));
}
// inputs pre-scaled by -2log2e: tanh(y) = 2*rcp(1 + exp2(y_scaled)) - 1
__device__ __forceinline__ float ftanh_s(float ys) {
  return fmaf(2.0f, __builtin_amdgcn_rcpf(1.0f + __builtin_amdgcn_exp2f(ys)), -1.0f);
}
__device__ __forceinline__ int ldv(const int* p) {
  return *(const volatile int*)p;
}

__global__ __launch_bounds__(NL * 64, 1) void gru5_kernel(Params p) {
  // ring: producer layer l (0..3) writes xring[l][c%RD]; consumer l+1 reads.
  // KK+1 rows so the consumer's t+1 prefetch is unguarded (row KK = junk).
  __shared__ float xring[NL - 1][RD][KK + 1][64];
  __shared__ float yp[NL];
  __shared__ int prog[NL - 1];   // chunks produced by layer l
  __shared__ int cons[NL - 1];   // chunks consumed by layer l+1

  const int tid = threadIdx.x;
  const int l = tid >> 6;          // wave index == layer
  const int lane = tid & 63;
  const int b = blockIdx.x;
  const int g = lane < GG ? lane : GG - 1;            // gate owned by lane
  const int gn = lane < HH ? lane + 2 * HH : GG - 1;  // n-gate column for unit lane

  if (tid < NL - 1) { prog[tid] = 0; cons[tid] = 0; }

  const float S1 = -1.44269504088896f;   // -log2(e)      (r/z rows)
  const float S2 = -2.88539008177793f;   // -2*log2(e)    (n rows)
  const float scg = (g < 2 * HH) ? S1 : S2;

  // ---- weights into registers, pre-scaled ----
  float whh_r[HH];
  {
    const float* W = p.whh[l];
    #pragma unroll
    for (int j = 0; j < HH; ++j) whh_r[j] = W[g * HH + j] * scg;
  }
  const float binit = (g >= 2 * HH) ? p.bhh[l][g] * S2 : 0.0f;

  float wnx[HH];
  float bnx = 0.0f;
  if (l < NL - 1) {
    const float* W = p.wih[l + 1];
    #pragma unroll
    for (int j = 0; j < HH; ++j) wnx[j] = W[g * HH + j] * scg;
    bnx = (p.bih[l + 1][g] + (g < 2 * HH ? p.bhh[l + 1][g] : 0.0f)) * scg;
  }
  float w0own = 0.f, b0own = 0.f, w0n = 0.f, b0n = 0.f;
  if (l == 0) {
    w0own = p.wih[0][g] * scg;
    b0own = (p.bih[0][g] + (g < 2 * HH ? p.bhh[0][g] : 0.0f)) * scg;
    w0n = p.wih[0][gn] * S2;
    b0n = p.bih[0][gn] * S2;          // b_ih only (b_hh_n stays in binit)
  }

  const int idx20 = ((lane + 20) & 63) << 2;   // bpermute byte indices
  const int idx40 = ((lane + 40) & 63) << 2;

  float hreg = 0.0f;               // lanes 0..19 carry h[unit]
  float hs[HH];                    // wave-uniform broadcast of h (SGPRs)
  #pragma unroll
  for (int j = 0; j < HH; ++j) hs[j] = 0.0f;

  const float* xrow = p.x + (size_t)b * TT;
  float* hout = p.out + (size_t)b * TT * HH;

  auto gru_step = [&](float xr, float xn) {
    float a0 = binit, a1 = 0.f, a2 = 0.f, a3 = 0.f;
    #pragma unroll
    for (int j = 0; j < HH; j += 4) {
      a0 = fmaf(whh_r[j],     hs[j],     a0);
      a1 = fmaf(whh_r[j + 1], hs[j + 1], a1);
      a2 = fmaf(whh_r[j + 2], hs[j + 2], a2);
      a3 = fmaf(whh_r[j + 3], hs[j + 3], a3);
    }
    const float gh = (a0 + a1) + (a2 + a3);   // scaled (W_hh h)[g] (+b_hh_n)
    const float sv = xr + gh;                 // scaled full preact (r/z rows)
    const float szn = shfl_idx(sv, idx20);    // z preact for unit lane
    const float ghn = shfl_idx(gh, idx40);    // n-gate h-proj (+b_hh_n)
    const float r = fsig_s(sv);
    const float z = fsig_s(szn);
    const float n = ftanh_s(fmaf(r, ghn, xn));
    hreg = fmaf(z, hreg - n, n);              // (1-z)*n + z*h
  };
  auto refresh_hs = [&]() {
    #pragma unroll
    for (int j = 0; j < HH; ++j) hs[j] = bcast(hreg, j);
  };
  auto proj_write = [&](float* dstrow) {      // next layer's xg row
    float c0 = bnx, c1 = 0.f;
    #pragma unroll
    for (int j = 0; j < HH; j += 2) {
      c0 = fmaf(wnx[j],     hs[j],     c0);
      c1 = fmaf(wnx[j + 1], hs[j + 1], c1);
    }
    dstrow[lane] = c0 + c1;
  };

  __syncthreads();                 // flags initialized

  // prime layer-0 x stage for chunk 0 (lanes 0..KK-1 hold the chunk's x)
  float xstage = 0.0f;
  if (l == 0 && lane < KK) xstage = xrow[lane];

  for (int c = 0; c < NC; ++c) {
    // --- sync: wait for input chunk; backpressure on ring slot reuse ---
    if (l > 0) {
      while (ldv(&prog[l - 1]) < c + 1) __builtin_amdgcn_s_sleep(1);
    }
    if (l < NL - 1) {
      while (ldv(&cons[l]) < c + 1 - RD) __builtin_amdgcn_s_sleep(1);
    }

    if (l == 0) {
      float* dst = &xring[0][c & (RD - 1)][0][0];
      // prefetch next chunk's x (a whole chunk of latency to hide)
      float xnl = 0.0f;
      if (lane < KK && c + 1 < NC) xnl = xrow[(c + 1) * KK + lane];
      for (int t = 0; t < KK; ++t) {
        const float xv = bcast_dyn(xstage, t);
        gru_step(fmaf(w0own, xv, b0own), fmaf(w0n, xv, b0n));
        refresh_hs();
        proj_write(dst + t * 64);
      }
      xstage = xnl;
    } else if (l < NL - 1) {
      const float* src = &xring[l - 1][c & (RD - 1)][0][0];
      float* dst = &xring[l][c & (RD - 1)][0][0];
      float xr_c = src[g];
      float xn_c = src[gn];
      for (int t = 0; t < KK; ++t) {
        const float* nsrc = src + (t + 1) * 64;   // row KK exists (junk, dead)
        const float xr_n = nsrc[g];
        const float xn_n = nsrc[gn];
        gru_step(xr_c, xn_c);
        refresh_hs();
        proj_write(dst + t * 64);
        xr_c = xr_n; xn_c = xn_n;
      }
    } else {
      const float* src = &xring[NL - 2][c & (RD - 1)][0][0];
      float* hp = hout + (size_t)c * KK * HH;
      float xr_c = src[g];
      float xn_c = src[gn];
      for (int t = 0; t < KK; ++t) {
        const float* nsrc = src + (t + 1) * 64;
        const float xr_n = nsrc[g];
        const float xn_n = nsrc[gn];
        gru_step(xr_c, xn_c);
        refresh_hs();                       // keeps hs fresh for next iter
        if (lane < HH) hp[t * HH + lane] = hreg;   // fire-and-forget
        xr_c = xr_n; xn_c = xn_n;
      }
    }

    // --- publish: producer flags chunk done; consumer frees ring slot ---
    if (l < NL - 1) {
      __threadfence_block();               // drain LDS writes before flag
      if (lane == 0) *(volatile int*)&prog[l] = c + 1;
    }
    if (l > 0) {
      if (lane == 0) *(volatile int*)&cons[l - 1] = c + 1;
    }
  }

  // ---- epilogue: h_n + y_hat partial (per wave, then one final barrier) ----
  if (lane < HH)
    p.out[(size_t)BB * TT * HH + (size_t)b * NL * HH + l * HH + lane] = hreg;
  float pp = (lane < HH) ? hreg * p.wout[l * HH + lane] : 0.0f;
  #pragma unroll
  for (int off = 32; off > 0; off >>= 1) pp += __shfl_down(pp, off);
  if (lane == 0) yp[l] = pp;

  __syncthreads();
  if (tid == 0) {
    float y = p.bout[0];
    #pragma unroll
    for (int ll = 0; ll < NL; ++ll) y += yp[ll];
    p.out[(size_t)BB * TT * HH + (size_t)BB * NL * HH + b] = y;
  }
}

extern "C" void kernel_launch(void* const* d_in, const int* in_sizes, int n_in,
                              void* d_out, int out_size, void* d_ws, size_t ws_size,
                              hipStream_t stream) {
  Params p;
  p.x = (const float*)d_in[0];
  for (int l = 0; l < NL; ++l) {
    p.wih[l] = (const float*)d_in[1 + 4 * l];
    p.whh[l] = (const float*)d_in[2 + 4 * l];
    p.bih[l] = (const float*)d_in[3 + 4 * l];
    p.bhh[l] = (const float*)d_in[4 + 4 * l];
  }
  p.wout = (const float*)d_in[1 + 4 * NL];
  p.bout = (const float*)d_in[2 + 4 * NL];
  p.out = (float*)d_out;

  gru5_kernel<<<BB, NL * 64, 0, stream>>>(p);
}